// Round 1
// baseline (413.595 us; speedup 1.0000x reference)
//
#include <hip/hip_runtime.h>

// HybridSatelliteNormalizer: per-(B,C) channel percentile normalization.
// x: (16,3,1024,1024) fp32. 48 channels x 1,048,576 px each.
//
// Strategy: exact k-th-value selection via 2-level histogram (1024 coarse x
// 1024 fine = 2^20 virtual bins), then a streaming apply pass.

#define HW (1024 * 1024)
#define NCH 48
#define BLOCKS_PER_CH 32
#define GRID_STREAM (NCH * BLOCKS_PER_CH)        // 1536 blocks
#define ELEMS_PER_BLOCK (HW / BLOCKS_PER_CH)     // 32768
#define F4_PER_THREAD (ELEMS_PER_BLOCK / 4 / 256) // 32

// ---------------- Pass A: coarse histogram (LDS, then global atomics) -------
__global__ __launch_bounds__(256) void k_hist(const float* __restrict__ x,
                                              unsigned* __restrict__ hist) {
    __shared__ unsigned lh[1024];
    const int t = threadIdx.x;
    for (int i = t; i < 1024; i += 256) lh[i] = 0u;
    __syncthreads();

    const int ch = blockIdx.x / BLOCKS_PER_CH;
    const long long base_f4 = (long long)blockIdx.x * (ELEMS_PER_BLOCK / 4);
    const float4* __restrict__ xv = (const float4*)x + base_f4;

#pragma unroll 4
    for (int i = 0; i < F4_PER_THREAD; ++i) {
        float4 v = xv[i * 256 + t];
        float f[4] = {v.x, v.y, v.z, v.w};
#pragma unroll
        for (int k = 0; k < 4; ++k) {
            if (f[k] > 1e-4f) {
                int j = (int)(f[k] * 1048576.0f);
                j = min(j, 1048575);
                atomicAdd(&lh[j >> 10], 1u);
            }
        }
    }
    __syncthreads();
    unsigned* gh = hist + ch * 1024;
    for (int i = t; i < 1024; i += 256) {
        unsigned c = lh[i];
        if (c) atomicAdd(&gh[i], c);
    }
}

// ---------------- Select coarse bin per channel -----------------------------
__global__ __launch_bounds__(1024) void k_select_coarse(const unsigned* __restrict__ hist,
                                                        int* __restrict__ info) {
    __shared__ unsigned s[1024];
    const int c = blockIdx.x, t = threadIdx.x;
    s[t] = hist[c * 1024 + t];
    __syncthreads();
    for (int off = 1; off < 1024; off <<= 1) {
        unsigned v = (t >= off) ? s[t - off] : 0u;
        __syncthreads();
        s[t] += v;
        __syncthreads();
    }
    const int n = (int)s[1023];
    if (t == 0) info[c * 8 + 0] = n;
    if (n <= 0) return;
    // reference: k = min(p*n//100 + 1, n); idx = max(k-1, 0) -> min(p*n/100, n-1)
    const int i2 = min((2 * n) / 100, n - 1);
    const int i98 = min((98 * n) / 100, n - 1);  // 98*n <= ~1.03e8, fits int32
    const unsigned excl = (t == 0) ? 0u : s[t - 1];
    const unsigned incl = s[t];
    if (excl <= (unsigned)i2 && (unsigned)i2 < incl) {
        info[c * 8 + 1] = t;             // coarse bin for v2
        info[c * 8 + 2] = i2 - (int)excl; // residual rank within bin
    }
    if (excl <= (unsigned)i98 && (unsigned)i98 < incl) {
        info[c * 8 + 3] = t;
        info[c * 8 + 4] = i98 - (int)excl;
    }
}

// ---------------- Pass B: fine sub-histograms of the 2 candidate bins -------
__global__ __launch_bounds__(256) void k_refine(const float* __restrict__ x,
                                                const int* __restrict__ info,
                                                unsigned* __restrict__ sub2,
                                                unsigned* __restrict__ sub98) {
    const int ch = blockIdx.x / BLOCKS_PER_CH;
    const int b2 = info[ch * 8 + 1];
    const int b98 = info[ch * 8 + 3];
    const long long base_f4 = (long long)blockIdx.x * (ELEMS_PER_BLOCK / 4);
    const float4* __restrict__ xv = (const float4*)x + base_f4;
    const int t = threadIdx.x;

#pragma unroll 4
    for (int i = 0; i < F4_PER_THREAD; ++i) {
        float4 v = xv[i * 256 + t];
        float f[4] = {v.x, v.y, v.z, v.w};
#pragma unroll
        for (int k = 0; k < 4; ++k) {
            if (f[k] > 1e-4f) {
                int j = (int)(f[k] * 1048576.0f);  // identical expr to pass A
                j = min(j, 1048575);
                const int cb = j >> 10, fb = j & 1023;
                if (cb == b2) atomicAdd(&sub2[ch * 1024 + fb], 1u);
                if (cb == b98) atomicAdd(&sub98[ch * 1024 + fb], 1u);
            }
        }
    }
}

// ---------------- Select fine bin -> per-channel params ---------------------
__global__ __launch_bounds__(1024) void k_select_fine(const unsigned* __restrict__ sub2,
                                                      const unsigned* __restrict__ sub98,
                                                      const int* __restrict__ info,
                                                      float* __restrict__ params) {
    __shared__ unsigned s[1024];
    __shared__ int fb2s, fb98s;
    const int c = blockIdx.x, t = threadIdx.x;
    const int n = info[c * 8 + 0];
    const int b2 = info[c * 8 + 1], r2 = info[c * 8 + 2];
    const int b98 = info[c * 8 + 3], r98 = info[c * 8 + 4];
    if (t == 0) { fb2s = 0; fb98s = 0; }

    // phase 1: scan sub2
    s[t] = sub2[c * 1024 + t];
    __syncthreads();
    for (int off = 1; off < 1024; off <<= 1) {
        unsigned v = (t >= off) ? s[t - off] : 0u;
        __syncthreads();
        s[t] += v;
        __syncthreads();
    }
    {
        const unsigned excl = (t == 0) ? 0u : s[t - 1];
        const unsigned incl = s[t];
        if (excl <= (unsigned)r2 && (unsigned)r2 < incl) fb2s = t;
    }
    __syncthreads();

    // phase 2: scan sub98
    s[t] = sub98[c * 1024 + t];
    __syncthreads();
    for (int off = 1; off < 1024; off <<= 1) {
        unsigned v = (t >= off) ? s[t - off] : 0u;
        __syncthreads();
        s[t] += v;
        __syncthreads();
    }
    {
        const unsigned excl = (t == 0) ? 0u : s[t - 1];
        const unsigned incl = s[t];
        if (excl <= (unsigned)r98 && (unsigned)r98 < incl) fb98s = t;
    }
    __syncthreads();

    if (t == 0) {
        const bool use = n > 100;
        const float v2 = ((float)(b2 * 1024 + fb2s) + 0.5f) * (1.0f / 1048576.0f);
        const float v98 = ((float)(b98 * 1024 + fb98s) + 0.5f) * (1.0f / 1048576.0f);
        const float mn = use ? v2 : 0.0f;
        const float mx = use ? v98 : 1.0f;
        const float sc = fmaxf(mx - mn, 1e-6f);
        const float mean3[3] = {0.485f, 0.456f, 0.406f};
        const float std3[3] = {0.229f, 0.224f, 0.225f};
        const int c3 = c % 3;
        float4 p;
        p.x = mn;
        p.y = 1.0f / sc;
        p.z = mean3[c3];
        p.w = 1.0f / std3[c3];
        ((float4*)params)[c] = p;
    }
}

// ---------------- Pass C: apply -------------------------------------------
__device__ __forceinline__ float apply_one(float x, float mn, float isc,
                                           float mean, float istd) {
    float y = (x - mn) * isc;
    y = fminf(fmaxf(y, 0.0f), 1.0f);
    // y^(1/2.2) via hw log2/exp2; exactly 0 at y==0 like the reference
    const float g = 0.45454547f;
    float p = (y > 0.0f) ? exp2f(g * log2f(y)) : 0.0f;
    return (p - mean) * istd;
}

__global__ __launch_bounds__(256) void k_apply(const float* __restrict__ x,
                                               float* __restrict__ out,
                                               const float4* __restrict__ params) {
    const int ch = blockIdx.x / BLOCKS_PER_CH;
    const float4 p = params[ch];
    const long long base_f4 = (long long)blockIdx.x * (ELEMS_PER_BLOCK / 4);
    const float4* __restrict__ xv = (const float4*)x + base_f4;
    float4* __restrict__ ov = (float4*)out + base_f4;
    const int t = threadIdx.x;

#pragma unroll 4
    for (int i = 0; i < F4_PER_THREAD; ++i) {
        float4 v = xv[i * 256 + t];
        float4 r;
        r.x = apply_one(v.x, p.x, p.y, p.z, p.w);
        r.y = apply_one(v.y, p.x, p.y, p.z, p.w);
        r.z = apply_one(v.z, p.x, p.y, p.z, p.w);
        r.w = apply_one(v.w, p.x, p.y, p.z, p.w);
        ov[i * 256 + t] = r;
    }
}

extern "C" void kernel_launch(void* const* d_in, const int* in_sizes, int n_in,
                              void* d_out, int out_size, void* d_ws, size_t ws_size,
                              hipStream_t stream) {
    const float* x = (const float*)d_in[0];
    float* out = (float*)d_out;

    // workspace layout (all u32/int/float = 4B):
    //   hist  : 48*1024 u32
    //   sub2  : 48*1024 u32
    //   sub98 : 48*1024 u32
    //   info  : 48*8 int   {n, b2, r2, b98, r98, -, -, -}
    //   params: 48*4 float {min, 1/scale, mean, 1/std}
    unsigned* hist = (unsigned*)d_ws;
    unsigned* sub2 = hist + NCH * 1024;
    unsigned* sub98 = sub2 + NCH * 1024;
    int* info = (int*)(sub98 + NCH * 1024);
    float* params = (float*)(info + NCH * 8);
    const size_t ws_used = (size_t)(3 * NCH * 1024 + NCH * 8 + NCH * 4) * 4;

    hipMemsetAsync(d_ws, 0, ws_used, stream);
    k_hist<<<GRID_STREAM, 256, 0, stream>>>(x, hist);
    k_select_coarse<<<NCH, 1024, 0, stream>>>(hist, info);
    k_refine<<<GRID_STREAM, 256, 0, stream>>>(x, info, sub2, sub98);
    k_select_fine<<<NCH, 1024, 0, stream>>>(sub2, sub98, info, params);
    k_apply<<<GRID_STREAM, 256, 0, stream>>>(x, out, (const float4*)params);
}